// Round 2
// baseline (110.142 us; speedup 1.0000x reference)
//
#include <hip/hip_runtime.h>

typedef unsigned short ushort_t;
typedef __bf16 bf16x8 __attribute__((ext_vector_type(8)));
typedef float f32x4 __attribute__((ext_vector_type(4)));
typedef void __attribute__((address_space(1))) gvoid_t;
typedef void __attribute__((address_space(3))) lvoid_t;

__device__ __forceinline__ float bflo(unsigned u) { return __builtin_bit_cast(float, u << 16); }
__device__ __forceinline__ float bfhi(unsigned u) { return __builtin_bit_cast(float, u & 0xffff0000u); }
__device__ __forceinline__ unsigned f2bf_bits(float f) {
  unsigned u = __builtin_bit_cast(unsigned, f);
  return (u + 0x7fffu + ((u >> 16) & 1u)) >> 16;
}
__device__ __forceinline__ ushort_t f2bf(float f) { return (ushort_t)f2bf_bits(f); }

// ---------------- prep: weight (o,c,k) f32 -> wb[k][o][c] bf16 ----------------
__global__ __launch_bounds__(256) void k_prep_w(const float* __restrict__ w,
                                                ushort_t* __restrict__ wb) {
  const int idx = blockIdx.x * 256 + threadIdx.x;  // (o,c) pair, 65536 total
  const float* src = w + (size_t)idx * 9;
  #pragma unroll
  for (int k = 0; k < 9; ++k)
    wb[(k << 16) + idx] = f2bf(src[k]);
}

// ---------------- prep: x (b,c,h,w) f32 -> xt[b][h][w][c] bf16 ----------------
__global__ __launch_bounds__(256) void k_prep_x(const float* __restrict__ x,
                                                ushort_t* __restrict__ xt) {
  __shared__ ushort_t tile[64][68];
  const int bid = blockIdx.x;             // 4b * 4ct * 64pt = 1024
  const int b = bid >> 8;
  const int ct = (bid >> 6) & 3;
  const int pt = bid & 63;
  const int t = threadIdx.x;
  const float* xb = x + ((size_t)(b * 256 + ct * 64)) * 4096 + pt * 64;
  #pragma unroll
  for (int i = 0; i < 16; ++i) {
    const int idx = t + 256 * i;
    const int c_l = idx >> 6, p_l = idx & 63;
    tile[c_l][p_l] = f2bf(xb[(size_t)c_l * 4096 + p_l]);
  }
  __syncthreads();
  ushort_t* xo = xt + ((size_t)(b * 4096 + pt * 64)) * 256 + ct * 64;
  #pragma unroll
  for (int i = 0; i < 16; ++i) {
    const int idx = t + 256 * i;
    const int p_l = idx >> 6, c_l = idx & 63;
    xo[(size_t)p_l * 256 + c_l] = tile[c_l][p_l];
  }
}

// ---------------- fused deform-sample + GEMM + GN partial stats ----------------
// block = half output row (b,h,wh): BM=32 (w), BN=256 (o). grid=512 -> 2 blocks/CU.
// K-loop: 9 taps x 4 chunks of 64 ch.
__global__ __launch_bounds__(256) void k_gemm(const float* __restrict__ off,
                                              const ushort_t* __restrict__ xt,
                                              const ushort_t* __restrict__ wb,
                                              float* __restrict__ y,
                                              float* __restrict__ stats) {
  __shared__ __attribute__((aligned(16))) ushort_t Abuf[32 * 64];   // [w][64c] swizzled, 4KB
  __shared__ __attribute__((aligned(16))) ushort_t Bbuf[256 * 64];  // [o][64c] swizzled, 32KB

  const int bid = blockIdx.x;  // 512 = 4b * 64h * 2wh
  const int b = bid >> 7;
  const int h = (bid >> 1) & 63;
  const int wh = bid & 1;
  const int t = threadIdx.x;
  const int wave = t >> 6;
  const int lane = t & 63;
  const int wq = lane >> 4;
  const int wr = lane & 15;

  const int s_w = t >> 3;   // sampling: local w column (0..31)
  const int c8 = t & 7;     // sampling: which 8-channel slice (of 8)

  const f32x4 zero = {0.f, 0.f, 0.f, 0.f};
  f32x4 acc[2][4];
  #pragma unroll
  for (int i = 0; i < 2; ++i)
    #pragma unroll
    for (int j = 0; j < 4; ++j) acc[i][j] = zero;

  const int gw = wh * 32 + s_w;  // global w of sampled column
  const float* offb = off + (size_t)b * 18 * 4096 + h * 64 + gw;
  const ushort_t* xtb = xt + (size_t)b * 4096 * 256;

  for (int k = 0; k < 9; ++k) {
    // bilinear meta for (gw, k) — reused over all channels
    const float offy = offb[(2 * k) * 4096];
    const float offx = offb[(2 * k + 1) * 4096];
    const float py = (float)(h - 1 + k / 3) + offy;
    const float px = (float)(gw - 1 + k % 3) + offx;
    const float fy = floorf(py), fx = floorf(px);
    const float ly = py - fy, lx = px - fx;
    const int iy0 = (int)fy, ix0 = (int)fx;
    const float vy0 = (iy0 >= 0 && iy0 < 64) ? 1.f : 0.f;
    const float vy1 = (iy0 >= -1 && iy0 < 63) ? 1.f : 0.f;
    const float vx0 = (ix0 >= 0 && ix0 < 64) ? 1.f : 0.f;
    const float vx1 = (ix0 >= -1 && ix0 < 63) ? 1.f : 0.f;
    const float w00 = (1.f - ly) * (1.f - lx) * vy0 * vx0;
    const float w01 = (1.f - ly) * lx * vy0 * vx1;
    const float w10 = ly * (1.f - lx) * vy1 * vx0;
    const float w11 = ly * lx * vy1 * vx1;
    const int cy0 = min(max(iy0, 0), 63), cy1 = min(max(iy0 + 1, 0), 63);
    const int cx0 = min(max(ix0, 0), 63), cx1 = min(max(ix0 + 1, 0), 63);
    const ushort_t* p00 = xtb + (cy0 * 64 + cx0) * 256;
    const ushort_t* p01 = xtb + (cy0 * 64 + cx1) * 256;
    const ushort_t* p10 = xtb + (cy1 * 64 + cx0) * 256;
    const ushort_t* p11 = xtb + (cy1 * 64 + cx1) * 256;

    for (int c0 = 0; c0 < 256; c0 += 64) {
      __syncthreads();  // previous chunk's frag reads done before overwrite
      // ---- stage A: sample 8 channels, pack bf16, swizzled ds_write_b128 ----
      {
        const int cc = c0 + c8 * 8;
        const uint4 q00 = *(const uint4*)(p00 + cc);
        const uint4 q01 = *(const uint4*)(p01 + cc);
        const uint4 q10 = *(const uint4*)(p10 + cc);
        const uint4 q11 = *(const uint4*)(p11 + cc);
        uint4 r;
        {
          float lo = w00 * bflo(q00.x) + w01 * bflo(q01.x) + w10 * bflo(q10.x) + w11 * bflo(q11.x);
          float hi = w00 * bfhi(q00.x) + w01 * bfhi(q01.x) + w10 * bfhi(q10.x) + w11 * bfhi(q11.x);
          r.x = f2bf_bits(lo) | (f2bf_bits(hi) << 16);
        }
        {
          float lo = w00 * bflo(q00.y) + w01 * bflo(q01.y) + w10 * bflo(q10.y) + w11 * bflo(q11.y);
          float hi = w00 * bfhi(q00.y) + w01 * bfhi(q01.y) + w10 * bfhi(q10.y) + w11 * bfhi(q11.y);
          r.y = f2bf_bits(lo) | (f2bf_bits(hi) << 16);
        }
        {
          float lo = w00 * bflo(q00.z) + w01 * bflo(q01.z) + w10 * bflo(q10.z) + w11 * bflo(q11.z);
          float hi = w00 * bfhi(q00.z) + w01 * bfhi(q01.z) + w10 * bfhi(q10.z) + w11 * bfhi(q11.z);
          r.z = f2bf_bits(lo) | (f2bf_bits(hi) << 16);
        }
        {
          float lo = w00 * bflo(q00.w) + w01 * bflo(q01.w) + w10 * bflo(q10.w) + w11 * bflo(q11.w);
          float hi = w00 * bfhi(q00.w) + w01 * bfhi(q01.w) + w10 * bfhi(q10.w) + w11 * bfhi(q11.w);
          r.w = f2bf_bits(lo) | (f2bf_bits(hi) << 16);
        }
        const int slot = c8 ^ (s_w & 7);
        *(uint4*)&Abuf[s_w * 64 + slot * 8] = r;
      }
      // ---- stage B: global_load_lds w=16, linear LDS dest, pre-swizzled global src ----
      #pragma unroll
      for (int i = 0; i < 8; ++i) {
        const int row = i * 32 + (t >> 3);
        const int slot = t & 7;
        const int cl = ((slot ^ (row & 7)) << 3);
        const ushort_t* g = wb + (((k << 8) + row) << 8) + c0 + cl;
        __builtin_amdgcn_global_load_lds((gvoid_t*)g,
                                         (lvoid_t*)((char*)Bbuf + i * 4096 + t * 16),
                                         16, 0, 0);
      }
      __syncthreads();
      // ---- MFMA: 2 K-steps of 32 ----
      #pragma unroll
      for (int ks = 0; ks < 2; ++ks) {
        bf16x8 af[2], bfr[4];
        #pragma unroll
        for (int tm = 0; tm < 2; ++tm) {
          const int row = tm * 16 + wr;
          const int slot = (ks * 4 + wq) ^ (row & 7);
          af[tm] = *(const bf16x8*)&Abuf[row * 64 + slot * 8];
        }
        #pragma unroll
        for (int tn = 0; tn < 4; ++tn) {
          const int row = wave * 64 + tn * 16 + wr;
          const int slot = (ks * 4 + wq) ^ (row & 7);
          bfr[tn] = *(const bf16x8*)&Bbuf[row * 64 + slot * 8];
        }
        #pragma unroll
        for (int tm = 0; tm < 2; ++tm)
          #pragma unroll
          for (int tn = 0; tn < 4; ++tn)
            acc[tm][tn] =
                __builtin_amdgcn_mfma_f32_16x16x32_bf16(af[tm], bfr[tn], acc[tm][tn], 0, 0, 0);
      }
    }
  }
  // ---- epilogue 1: y write [b][s][o]; D layout col=lane&15, row=(lane>>4)*4+r ----
  float* yb = y + ((size_t)(b * 4096 + h * 64 + wh * 32)) * 256;
  #pragma unroll
  for (int tm = 0; tm < 2; ++tm) {
    #pragma unroll
    for (int tn = 0; tn < 4; ++tn) {
      const int o = wave * 64 + tn * 16 + wr;
      #pragma unroll
      for (int r2 = 0; r2 < 4; ++r2) {
        const int ww = tm * 16 + wq * 4 + r2;
        yb[ww * 256 + o] = acc[tm][tn][r2];
      }
    }
  }
  // ---- epilogue 2: fused GN partial stats (sum, sumsq per group) ----
  #pragma unroll
  for (int tn = 0; tn < 4; ++tn) {
    float sum = 0.f, ss = 0.f;
    #pragma unroll
    for (int tm = 0; tm < 2; ++tm)
      #pragma unroll
      for (int r2 = 0; r2 < 4; ++r2) {
        const float v = acc[tm][tn][r2];
        sum += v;
        ss += v * v;
      }
    // reduce across the 4 wq sub-rows (same o column)
    sum += __shfl_xor(sum, 16, 64);
    ss += __shfl_xor(ss, 16, 64);
    sum += __shfl_xor(sum, 32, 64);
    ss += __shfl_xor(ss, 32, 64);
    // reduce across o within the 8-wide group (wr&7)
    #pragma unroll
    for (int d = 1; d < 8; d <<= 1) {
      sum += __shfl_xor(sum, d, 64);
      ss += __shfl_xor(ss, d, 64);
    }
    if (wq == 0 && (wr & 7) == 0) {
      const int g = wave * 8 + tn * 2 + (wr >> 3);
      atomicAdd(&stats[(b * 32 + g) * 2], sum);
      atomicAdd(&stats[(b * 32 + g) * 2 + 1], ss);
    }
  }
}

// ---------------- GN apply + ReLU, transpose [b][s][o] -> [b][o][s] ----------------
__global__ __launch_bounds__(256) void k_apply(const float* __restrict__ y,
                                               const float* __restrict__ stats,
                                               const float* __restrict__ gamma,
                                               const float* __restrict__ beta,
                                               float* __restrict__ out) {
  __shared__ float tile[64][65];
  __shared__ float sm[8], sr[8], sg[64], sb[64];
  const int bid = blockIdx.x;  // b(4) x st(64) x ot(4) = 1024
  const int b = bid >> 8;
  const int st = (bid >> 2) & 63;
  const int ot = bid & 3;
  const int t = threadIdx.x;
  if (t < 8) {
    const int g = ot * 8 + t;
    const float s1 = stats[(b * 32 + g) * 2];
    const float s2 = stats[(b * 32 + g) * 2 + 1];
    const float mean = s1 * (1.f / 32768.f);
    const float var = s2 * (1.f / 32768.f) - mean * mean;
    sm[t] = mean;
    sr[t] = rsqrtf(var + 1e-5f);
  }
  if (t < 64) {
    sg[t] = gamma[ot * 64 + t];
    sb[t] = beta[ot * 64 + t];
  }
  const float* yb = y + ((size_t)(b * 4096 + st * 64)) * 256 + ot * 64;
  #pragma unroll
  for (int i = 0; i < 16; ++i) {
    const int idx = t + 256 * i;
    const int s_l = idx >> 6, o_l = idx & 63;
    tile[s_l][o_l] = yb[(size_t)s_l * 256 + o_l];
  }
  __syncthreads();
  float* ob = out + ((size_t)(b * 256 + ot * 64)) * 4096 + st * 64;
  #pragma unroll
  for (int i = 0; i < 16; ++i) {
    const int idx = t + 256 * i;
    const int o_l = idx >> 6, s_l = idx & 63;
    const int g = o_l >> 3;
    float v = (tile[s_l][o_l] - sm[g]) * sr[g] * sg[o_l] + sb[o_l];
    v = v > 0.f ? v : 0.f;
    ob[(size_t)o_l * 4096 + s_l] = v;
  }
}

extern "C" void kernel_launch(void* const* d_in, const int* in_sizes, int n_in,
                              void* d_out, int out_size, void* d_ws, size_t ws_size,
                              hipStream_t stream) {
  const float* x = (const float*)d_in[0];       // (4,256,64,64)
  const float* off = (const float*)d_in[1];     // (4,18,64,64)
  const float* w = (const float*)d_in[2];       // (256,256,3,3)
  const float* gamma = (const float*)d_in[3];   // (256)
  const float* beta = (const float*)d_in[4];    // (256)
  float* out = (float*)d_out;

  char* ws = (char*)d_ws;
  float* y = (float*)(ws);                        // 16,777,216 B  [b][s][o] f32
  ushort_t* xt = (ushort_t*)(ws + 16777216);      //  8,388,608 B  [b][h][w][c] bf16
  ushort_t* wb = (ushort_t*)(ws + 25165824);      //  1,179,648 B  [k][o][c] bf16
  float* stats = (float*)(ws + 26345472);         //      1,024 B  [b][g]{sum,ss}

  hipMemsetAsync(stats, 0, 1024, stream);
  k_prep_w<<<256, 256, 0, stream>>>(w, wb);
  k_prep_x<<<1024, 256, 0, stream>>>(x, xt);
  k_gemm<<<512, 256, 0, stream>>>(off, xt, wb, y, stats);
  k_apply<<<1024, 256, 0, stream>>>(y, stats, gamma, beta, out);
}

// Round 3
// 97.412 us; speedup vs baseline: 1.1307x; 1.1307x over previous
//
#include <hip/hip_runtime.h>

typedef unsigned short ushort_t;
typedef __bf16 bf16x8 __attribute__((ext_vector_type(8)));
typedef float f32x4 __attribute__((ext_vector_type(4)));
typedef void __attribute__((address_space(1))) gvoid_t;
typedef void __attribute__((address_space(3))) lvoid_t;

__device__ __forceinline__ float bflo(unsigned u) { return __builtin_bit_cast(float, u << 16); }
__device__ __forceinline__ float bfhi(unsigned u) { return __builtin_bit_cast(float, u & 0xffff0000u); }
__device__ __forceinline__ unsigned f2bf_bits(float f) {
  unsigned u = __builtin_bit_cast(unsigned, f);
  return (u + 0x7fffu + ((u >> 16) & 1u)) >> 16;
}
__device__ __forceinline__ ushort_t f2bf(float f) { return (ushort_t)f2bf_bits(f); }

// ---------------- prep: weight (o,c,k) f32 -> wb[k][o][c] bf16 ----------------
__global__ __launch_bounds__(256) void k_prep_w(const float* __restrict__ w,
                                                ushort_t* __restrict__ wb) {
  const int idx = blockIdx.x * 256 + threadIdx.x;  // (o,c) pair, 65536 total
  const float* src = w + (size_t)idx * 9;
  #pragma unroll
  for (int k = 0; k < 9; ++k)
    wb[(k << 16) + idx] = f2bf(src[k]);
}

// ---------------- prep: x (b,c,h,w) f32 -> xt[b][h][w][c] bf16 ----------------
__global__ __launch_bounds__(256) void k_prep_x(const float* __restrict__ x,
                                                ushort_t* __restrict__ xt) {
  __shared__ ushort_t tile[64][68];
  const int bid = blockIdx.x;             // 4b * 4ct * 64pt = 1024
  const int b = bid >> 8;
  const int ct = (bid >> 6) & 3;
  const int pt = bid & 63;
  const int t = threadIdx.x;
  const float* xb = x + ((size_t)(b * 256 + ct * 64)) * 4096 + pt * 64;
  #pragma unroll
  for (int i = 0; i < 16; ++i) {
    const int idx = t + 256 * i;
    const int c_l = idx >> 6, p_l = idx & 63;
    tile[c_l][p_l] = f2bf(xb[(size_t)c_l * 4096 + p_l]);
  }
  __syncthreads();
  ushort_t* xo = xt + ((size_t)(b * 4096 + pt * 64)) * 256 + ct * 64;
  #pragma unroll
  for (int i = 0; i < 16; ++i) {
    const int idx = t + 256 * i;
    const int p_l = idx >> 6, c_l = idx & 63;
    xo[(size_t)p_l * 256 + c_l] = tile[c_l][p_l];
  }
}

// bilinear meta for one (h, w, tap) — weights and gather base offsets (in ushorts)
struct SMeta {
  float w00, w01, w10, w11;
  int i00, i01, i10, i11;
};
__device__ __forceinline__ SMeta meta_for(int h, int gw, int k, float oy, float ox) {
  SMeta m;
  const float py = (float)(h - 1 + k / 3) + oy;
  const float px = (float)(gw - 1 + k % 3) + ox;
  const float fy = floorf(py), fx = floorf(px);
  const float ly = py - fy, lx = px - fx;
  const int iy0 = (int)fy, ix0 = (int)fx;
  const float vy0 = (iy0 >= 0 && iy0 < 64) ? 1.f : 0.f;
  const float vy1 = (iy0 >= -1 && iy0 < 63) ? 1.f : 0.f;
  const float vx0 = (ix0 >= 0 && ix0 < 64) ? 1.f : 0.f;
  const float vx1 = (ix0 >= -1 && ix0 < 63) ? 1.f : 0.f;
  m.w00 = (1.f - ly) * (1.f - lx) * vy0 * vx0;
  m.w01 = (1.f - ly) * lx * vy0 * vx1;
  m.w10 = ly * (1.f - lx) * vy1 * vx0;
  m.w11 = ly * lx * vy1 * vx1;
  const int cy0 = min(max(iy0, 0), 63), cy1 = min(max(iy0 + 1, 0), 63);
  const int cx0 = min(max(ix0, 0), 63), cx1 = min(max(ix0 + 1, 0), 63);
  m.i00 = (cy0 * 64 + cx0) * 256;
  m.i01 = (cy0 * 64 + cx1) * 256;
  m.i10 = (cy1 * 64 + cx0) * 256;
  m.i11 = (cy1 * 64 + cx1) * 256;
  return m;
}

__device__ __forceinline__ unsigned lerp_pack(unsigned a, unsigned b, unsigned c, unsigned d,
                                              float w00, float w01, float w10, float w11) {
  float lo = w00 * bflo(a) + w01 * bflo(b) + w10 * bflo(c) + w11 * bflo(d);
  float hi = w00 * bfhi(a) + w01 * bfhi(b) + w10 * bfhi(c) + w11 * bfhi(d);
  return f2bf_bits(lo) | (f2bf_bits(hi) << 16);
}

// ---------------- fused deform-sample + GEMM + GN partial stats ----------------
// block = one output row (b,h): BM=64 (w), BN=256 (o), 8 waves. grid=256.
// 36 chunks (9 taps x 4 c-slices of 64), double-buffered LDS, 2-phase pipeline.
__global__ __launch_bounds__(512) void k_gemm(const float* __restrict__ off,
                                              const ushort_t* __restrict__ xt,
                                              const ushort_t* __restrict__ wb,
                                              float* __restrict__ y,
                                              float* __restrict__ stats) {
  __shared__ __attribute__((aligned(16))) ushort_t Abuf[2][64 * 64];   // 2 x 8KB
  __shared__ __attribute__((aligned(16))) ushort_t Bbuf[2][256 * 64];  // 2 x 32KB

  const int bid = blockIdx.x;  // 256 = 4b * 64h
  const int b = bid >> 6;
  const int h = bid & 63;
  const int t = threadIdx.x;   // 0..511
  const int wave = t >> 6;
  const int lane = t & 63;
  const int wq = lane >> 4;
  const int wr = lane & 15;
  const int wm = wave >> 2;    // M half (0..1)
  const int wn = wave & 3;     // N quarter (0..3)

  const int s_w = t >> 3;  // sampling: w column (0..63)
  const int c8 = t & 7;    // sampling: 8-channel slice (0..7)

  const f32x4 zero = {0.f, 0.f, 0.f, 0.f};
  f32x4 acc[2][4];
  #pragma unroll
  for (int i = 0; i < 2; ++i)
    #pragma unroll
    for (int j = 0; j < 4; ++j) acc[i][j] = zero;

  const ushort_t* xtb = xt + (size_t)b * 4096 * 256;

  // hoist all 18 offset values into registers (kills per-chunk dependent load chain)
  float offy[9], offx[9];
  {
    const float* offb = off + (size_t)b * 18 * 4096 + h * 64 + s_w;
    #pragma unroll
    for (int k = 0; k < 9; ++k) {
      offy[k] = offb[(2 * k) * 4096];
      offx[k] = offb[(2 * k + 1) * 4096];
    }
  }

  // ---- prologue: stage chunk 0 into buffer 0 ----
  {
    const SMeta m = meta_for(h, s_w, 0, offy[0], offx[0]);
    const int cc = c8 * 8;
    const uint4 q00 = *(const uint4*)(xtb + m.i00 + cc);
    const uint4 q01 = *(const uint4*)(xtb + m.i01 + cc);
    const uint4 q10 = *(const uint4*)(xtb + m.i10 + cc);
    const uint4 q11 = *(const uint4*)(xtb + m.i11 + cc);
    #pragma unroll
    for (int i = 0; i < 4; ++i) {
      const int idx = i * 512 + t;
      const int row = idx >> 3, slot = idx & 7;
      const ushort_t* g = wb + row * 256 + ((slot ^ (row & 7)) << 3);
      __builtin_amdgcn_global_load_lds((gvoid_t*)g, (lvoid_t*)((char*)Bbuf[0] + idx * 16), 16, 0, 0);
    }
    uint4 r;
    r.x = lerp_pack(q00.x, q01.x, q10.x, q11.x, m.w00, m.w01, m.w10, m.w11);
    r.y = lerp_pack(q00.y, q01.y, q10.y, q11.y, m.w00, m.w01, m.w10, m.w11);
    r.z = lerp_pack(q00.z, q01.z, q10.z, q11.z, m.w00, m.w01, m.w10, m.w11);
    r.w = lerp_pack(q00.w, q01.w, q10.w, q11.w, m.w00, m.w01, m.w10, m.w11);
    *(uint4*)&Abuf[0][s_w * 64 + ((c8 ^ (s_w & 7)) << 3)] = r;
  }
  __syncthreads();

  // ---- main loop: 36 chunks, fully unrolled (k, c0, cur all compile-time) ----
  #pragma unroll
  for (int n = 0; n < 36; ++n) {
    const int cur = n & 1;
    const int nb = cur ^ 1;
    // prefetch chunk n+1: issue gathers + B global_load_lds BEFORE the MFMA phase
    uint4 q00, q01, q10, q11;
    SMeta m;
    if (n < 35) {
      const int kn = (n + 1) >> 2;
      const int c0n = ((n + 1) & 3) << 6;
      m = meta_for(h, s_w, kn, offy[kn], offx[kn]);
      const int cc = c0n + c8 * 8;
      q00 = *(const uint4*)(xtb + m.i00 + cc);
      q01 = *(const uint4*)(xtb + m.i01 + cc);
      q10 = *(const uint4*)(xtb + m.i10 + cc);
      q11 = *(const uint4*)(xtb + m.i11 + cc);
      #pragma unroll
      for (int i = 0; i < 4; ++i) {
        const int idx = i * 512 + t;
        const int row = idx >> 3, slot = idx & 7;
        const ushort_t* g = wb + (kn << 16) + row * 256 + c0n + ((slot ^ (row & 7)) << 3);
        __builtin_amdgcn_global_load_lds((gvoid_t*)g, (lvoid_t*)((char*)Bbuf[nb] + idx * 16), 16, 0, 0);
      }
    }
    // compute chunk n from buf[cur]
    #pragma unroll
    for (int ks = 0; ks < 2; ++ks) {
      bf16x8 af[2], bfr[4];
      #pragma unroll
      for (int tm = 0; tm < 2; ++tm) {
        const int row = wm * 32 + tm * 16 + wr;
        const int slot = (ks * 4 + wq) ^ (row & 7);
        af[tm] = *(const bf16x8*)&Abuf[cur][row * 64 + slot * 8];
      }
      #pragma unroll
      for (int tn = 0; tn < 4; ++tn) {
        const int row = wn * 64 + tn * 16 + wr;
        const int slot = (ks * 4 + wq) ^ (row & 7);
        bfr[tn] = *(const bf16x8*)&Bbuf[cur][row * 64 + slot * 8];
      }
      #pragma unroll
      for (int tm = 0; tm < 2; ++tm)
        #pragma unroll
        for (int tn = 0; tn < 4; ++tn)
          acc[tm][tn] =
              __builtin_amdgcn_mfma_f32_16x16x32_bf16(af[tm], bfr[tn], acc[tm][tn], 0, 0, 0);
    }
    // pack + LDS-write next A tile (waits only on the 4 gather loads)
    if (n < 35) {
      uint4 r;
      r.x = lerp_pack(q00.x, q01.x, q10.x, q11.x, m.w00, m.w01, m.w10, m.w11);
      r.y = lerp_pack(q00.y, q01.y, q10.y, q11.y, m.w00, m.w01, m.w10, m.w11);
      r.z = lerp_pack(q00.z, q01.z, q10.z, q11.z, m.w00, m.w01, m.w10, m.w11);
      r.w = lerp_pack(q00.w, q01.w, q10.w, q11.w, m.w00, m.w01, m.w10, m.w11);
      *(uint4*)&Abuf[nb][s_w * 64 + ((c8 ^ (s_w & 7)) << 3)] = r;
    }
    __syncthreads();
  }

  // ---- epilogue 1: y write [b][s][o]; D layout col=lane&15, row=(lane>>4)*4+r ----
  float* yb = y + ((size_t)(b * 4096 + h * 64)) * 256;
  #pragma unroll
  for (int tm = 0; tm < 2; ++tm) {
    #pragma unroll
    for (int tn = 0; tn < 4; ++tn) {
      const int o = wn * 64 + tn * 16 + wr;
      #pragma unroll
      for (int r2 = 0; r2 < 4; ++r2) {
        const int ww = wm * 32 + tm * 16 + wq * 4 + r2;
        yb[ww * 256 + o] = acc[tm][tn][r2];
      }
    }
  }
  // ---- epilogue 2: fused GN partial stats ----
  #pragma unroll
  for (int tn = 0; tn < 4; ++tn) {
    float sum = 0.f, ss = 0.f;
    #pragma unroll
    for (int tm = 0; tm < 2; ++tm)
      #pragma unroll
      for (int r2 = 0; r2 < 4; ++r2) {
        const float v = acc[tm][tn][r2];
        sum += v;
        ss += v * v;
      }
    sum += __shfl_xor(sum, 16, 64);
    ss += __shfl_xor(ss, 16, 64);
    sum += __shfl_xor(sum, 32, 64);
    ss += __shfl_xor(ss, 32, 64);
    #pragma unroll
    for (int d = 1; d < 8; d <<= 1) {
      sum += __shfl_xor(sum, d, 64);
      ss += __shfl_xor(ss, d, 64);
    }
    if (wq == 0 && (wr & 7) == 0) {
      const int g = wn * 8 + tn * 2 + (wr >> 3);
      atomicAdd(&stats[(b * 32 + g) * 2], sum);
      atomicAdd(&stats[(b * 32 + g) * 2 + 1], ss);
    }
  }
}

// ---------------- GN apply + ReLU, transpose [b][s][o] -> [b][o][s] ----------------
__global__ __launch_bounds__(256) void k_apply(const float* __restrict__ y,
                                               const float* __restrict__ stats,
                                               const float* __restrict__ gamma,
                                               const float* __restrict__ beta,
                                               float* __restrict__ out) {
  __shared__ float tile[64][65];
  __shared__ float sm[8], sr[8], sg[64], sb[64];
  const int bid = blockIdx.x;  // b(4) x st(64) x ot(4) = 1024
  const int b = bid >> 8;
  const int st = (bid >> 2) & 63;
  const int ot = bid & 3;
  const int t = threadIdx.x;
  if (t < 8) {
    const int g = ot * 8 + t;
    const float s1 = stats[(b * 32 + g) * 2];
    const float s2 = stats[(b * 32 + g) * 2 + 1];
    const float mean = s1 * (1.f / 32768.f);
    const float var = s2 * (1.f / 32768.f) - mean * mean;
    sm[t] = mean;
    sr[t] = rsqrtf(var + 1e-5f);
  }
  if (t < 64) {
    sg[t] = gamma[ot * 64 + t];
    sb[t] = beta[ot * 64 + t];
  }
  const float* yb = y + ((size_t)(b * 4096 + st * 64)) * 256 + ot * 64;
  #pragma unroll
  for (int i = 0; i < 16; ++i) {
    const int idx = t + 256 * i;
    const int s_l = idx >> 6, o_l = idx & 63;
    tile[s_l][o_l] = yb[(size_t)s_l * 256 + o_l];
  }
  __syncthreads();
  float* ob = out + ((size_t)(b * 256 + ot * 64)) * 4096 + st * 64;
  #pragma unroll
  for (int i = 0; i < 16; ++i) {
    const int idx = t + 256 * i;
    const int o_l = idx >> 6, s_l = idx & 63;
    const int g = o_l >> 3;
    float v = (tile[s_l][o_l] - sm[g]) * sr[g] * sg[o_l] + sb[o_l];
    v = v > 0.f ? v : 0.f;
    ob[(size_t)o_l * 4096 + s_l] = v;
  }
}

extern "C" void kernel_launch(void* const* d_in, const int* in_sizes, int n_in,
                              void* d_out, int out_size, void* d_ws, size_t ws_size,
                              hipStream_t stream) {
  const float* x = (const float*)d_in[0];       // (4,256,64,64)
  const float* off = (const float*)d_in[1];     // (4,18,64,64)
  const float* w = (const float*)d_in[2];       // (256,256,3,3)
  const float* gamma = (const float*)d_in[3];   // (256)
  const float* beta = (const float*)d_in[4];    // (256)
  float* out = (float*)d_out;

  char* ws = (char*)d_ws;
  float* y = (float*)(ws);                        // 16,777,216 B  [b][s][o] f32
  ushort_t* xt = (ushort_t*)(ws + 16777216);      //  8,388,608 B  [b][h][w][c] bf16
  ushort_t* wb = (ushort_t*)(ws + 25165824);      //  1,179,648 B  [k][o][c] bf16
  float* stats = (float*)(ws + 26345472);         //      1,024 B  [b][g]{sum,ss}

  hipMemsetAsync(stats, 0, 1024, stream);
  k_prep_w<<<256, 256, 0, stream>>>(w, wb);
  k_prep_x<<<1024, 256, 0, stream>>>(x, xt);
  k_gemm<<<256, 512, 0, stream>>>(off, xt, wb, y, stats);
  k_apply<<<1024, 256, 0, stream>>>(y, stats, gamma, beta, out);
}